// Round 1
// baseline (770.872 us; speedup 1.0000x reference)
//
#include <hip/hip_runtime.h>
#include <cstdint>
#include <cstddef>

typedef short short8 __attribute__((ext_vector_type(8)));
typedef float f32x4 __attribute__((ext_vector_type(4)));
typedef unsigned short us4 __attribute__((ext_vector_type(4)));

// ---------- helpers ----------
__device__ __forceinline__ unsigned short f2bf(float f) {
  unsigned int u = __float_as_uint(f);
  unsigned int r = (u + 0x7fffu + ((u >> 16) & 1u)) >> 16;  // RNE
  return (unsigned short)r;
}
__device__ __forceinline__ float bf2f(unsigned short s) {
  return __uint_as_float(((unsigned int)s) << 16);
}
// async global->LDS, 16B per lane. HW semantics: LDS dest = wave-uniform base + lane*16.
__device__ __forceinline__ void gload_lds16(const void* g, void* l) {
  auto gp = reinterpret_cast<const __attribute__((address_space(1))) char*>(
      reinterpret_cast<uintptr_t>(g));
  auto lp = reinterpret_cast<__attribute__((address_space(3))) char*>(
      reinterpret_cast<uintptr_t>(l));
  __builtin_amdgcn_global_load_lds(gp, lp, 16, 0, 0);
}

// ---------- weight reconstruction: w' = (LM@RM + W) * F * scale (bf16), b' = b*F*scale ----------
__global__ __launch_bounds__(256) void prep_weights(
    const float* __restrict__ W, const float* __restrict__ bias,
    const float* __restrict__ LM, const float* __restrict__ RM,
    const float* __restrict__ F, float scale,
    unsigned short* __restrict__ Wout, float* __restrict__ bout) {
  const int o = blockIdx.x;      // output row 0..1023
  const int tid = threadIdx.x;   // 256
  __shared__ float lm[64];
  if (tid < 64) lm[tid] = LM[o * 64 + tid];
  __syncthreads();
  const float f = F[o] * scale;
#pragma unroll
  for (int j = 0; j < 4; ++j) {
    const int i = tid + j * 256;
    float acc = W[o * 1024 + i];
#pragma unroll 16
    for (int k = 0; k < 64; ++k) acc = fmaf(lm[k], RM[k * 1024 + i], acc);
    Wout[o * 1024 + i] = f2bf(acc * f);
  }
  if (tid == 0) bout[o] = bias[o] * f;
}

// ---------- f32 -> bf16 cast ----------
__global__ __launch_bounds__(256) void cast_x(const float* __restrict__ x,
                                              unsigned short* __restrict__ y, int n4) {
  const int i = blockIdx.x * 256 + threadIdx.x;
  if (i >= n4) return;
  f32x4 v = *(const f32x4*)(x + (size_t)i * 4);
  us4 o;
  o[0] = f2bf(v[0]); o[1] = f2bf(v[1]); o[2] = f2bf(v[2]); o[3] = f2bf(v[3]);
  *(us4*)(y + (size_t)i * 4) = o;
}

// ---------- GEMM: C[m][n] = sum_k A[m][k]*Bw[n][k] + bias[n] ----------
// 128x128 block tile, BK=64, 4 waves each 64x64 (4x4 of 16x16x32 mfma).
// MODE 0: scatter to qkv bf16 [p][b][h][s][d];  MODE 1: f32 row-major out.
template <int MODE>
__global__ __launch_bounds__(256) void gemm_bt(const unsigned short* __restrict__ A,
                                               const unsigned short* __restrict__ Bw,
                                               const float* __restrict__ bias,
                                               void* __restrict__ Cout,
                                               int M, int N, int K) {
  __shared__ unsigned short sA[128 * 64];
  __shared__ unsigned short sB[128 * 64];
  const int tid = threadIdx.x;
  const int w = tid >> 6;
  const int lane = tid & 63;
  const int quad = lane >> 4;
  const int ln = lane & 15;
  const int bm = blockIdx.x, bn = blockIdx.y;
  const int wm = w >> 1, wn = w & 1;

  f32x4 acc[4][4];
#pragma unroll
  for (int a = 0; a < 4; ++a)
#pragma unroll
    for (int b = 0; b < 4; ++b) acc[a][b] = (f32x4){0.f, 0.f, 0.f, 0.f};

  const size_t Kb = (size_t)K * 2;
  const char* Agb = (const char*)A + (size_t)bm * 128 * Kb;
  const char* Bgb = (const char*)Bw + (size_t)bn * 128 * Kb;
  char* sAb = (char*)sA;
  char* sBb = (char*)sB;

  for (int k0 = 0; k0 < K; k0 += 64) {
    __syncthreads();  // LDS safe to overwrite
#pragma unroll
    for (int i = 0; i < 4; ++i) {
      const int Lb = w * 4096 + i * 1024 + lane * 16;  // linear byte in tile
      const int r = Lb >> 7;                           // tile row (128B rows)
      const int cb = Lb & 127;                         // byte in row
      gload_lds16(Agb + (size_t)r * Kb + (size_t)k0 * 2 + cb, sAb + Lb);
      gload_lds16(Bgb + (size_t)r * Kb + (size_t)k0 * 2 + cb, sBb + Lb);
    }
    __syncthreads();  // staging visible (compiler drains vmcnt before barrier)
#pragma unroll
    for (int kk = 0; kk < 2; ++kk) {
      short8 af[4], bfv[4];
#pragma unroll
      for (int t = 0; t < 4; ++t) {
        af[t]  = *(const short8*)(sAb + (wm * 64 + t * 16 + ln) * 128 + kk * 64 + quad * 16);
        bfv[t] = *(const short8*)(sBb + (wn * 64 + t * 16 + ln) * 128 + kk * 64 + quad * 16);
      }
#pragma unroll
      for (int mt = 0; mt < 4; ++mt)
#pragma unroll
        for (int nt = 0; nt < 4; ++nt)
          acc[mt][nt] = __builtin_amdgcn_mfma_f32_16x16x32_bf16(af[mt], bfv[nt], acc[mt][nt], 0, 0, 0);
    }
  }

  // epilogue. C/D layout: col = ln, row = quad*4 + reg (measured m89/m91)
  if (MODE == 0) {
    unsigned short* out = (unsigned short*)Cout;
#pragma unroll
    for (int mt = 0; mt < 4; ++mt) {
#pragma unroll
      for (int nt = 0; nt < 4; ++nt) {
        const int gn = bn * 128 + wn * 64 + nt * 16 + ln;
        const float bv = bias[gn];
        const int pidx = gn >> 10, rem = gn & 1023;
        const int hh = rem >> 6, dd = rem & 63;
#pragma unroll
        for (int r = 0; r < 4; ++r) {
          const int gm = bm * 128 + wm * 64 + mt * 16 + quad * 4 + r;
          const int bb = gm >> 10, ss = gm & 1023;
          const size_t off = ((((size_t)pidx * 16 + bb) * 16 + hh) * 1024 + ss) * 64 + dd;
          out[off] = f2bf(acc[mt][nt][r] + bv);
        }
      }
    }
  } else {
    float* out = (float*)Cout;
#pragma unroll
    for (int mt = 0; mt < 4; ++mt) {
#pragma unroll
      for (int nt = 0; nt < 4; ++nt) {
        const int gn = bn * 128 + wn * 64 + nt * 16 + ln;
        const float bv = bias[gn];
#pragma unroll
        for (int r = 0; r < 4; ++r) {
          const int gm = bm * 128 + wm * 64 + mt * 16 + quad * 4 + r;
          out[(size_t)gm * N + gn] = acc[mt][nt][r] + bv;
        }
      }
    }
  }
}

// ---------- flash attention: one block per (bh, 64-row q tile) ----------
// q pre-scaled by 1/sqrt(64) in prep. qkv layout [bh][s][d] bf16, S=1024, d=64.
__global__ __launch_bounds__(256) void attn(const unsigned short* __restrict__ Qb,
                                            const unsigned short* __restrict__ Kb_,
                                            const unsigned short* __restrict__ Vb,
                                            unsigned short* __restrict__ ctx) {
  __shared__ unsigned short sQ[64 * 64];
  __shared__ unsigned short sK[64 * 64];
  __shared__ unsigned short sV[64 * 72];  // transposed [d][s], stride 72 (16B-aligned rows)
  __shared__ unsigned short sP[64 * 72];  // [q_row][k], stride 72
  const int tid = threadIdx.x;
  const int w = tid >> 6, lane = tid & 63, quad = lane >> 4, ln = lane & 15;
  const int qt = blockIdx.x, bh = blockIdx.y;
  const int b = bh >> 4, h = bh & 15;

  char* sQb = (char*)sQ;
  char* sKb = (char*)sK;
  char* sVb = (char*)sV;
  char* sPb = (char*)sP;

  const char* Qg = (const char*)(Qb + ((size_t)bh * 1024 + qt * 64) * 64);
#pragma unroll
  for (int i = 0; i < 2; ++i) {
    const int Lb = w * 2048 + i * 1024 + lane * 16;
    gload_lds16(Qg + Lb, sQb + Lb);
  }

  f32x4 accO[4];
#pragma unroll
  for (int nt = 0; nt < 4; ++nt) accO[nt] = (f32x4){0.f, 0.f, 0.f, 0.f};
  float mrow[4] = {-3e38f, -3e38f, -3e38f, -3e38f};
  float lrow[4] = {0.f, 0.f, 0.f, 0.f};

  for (int kt = 0; kt < 16; ++kt) {
    __syncthreads();  // previous tile's compute done
    const char* Kg = (const char*)(Kb_ + ((size_t)bh * 1024 + kt * 64) * 64);
#pragma unroll
    for (int i = 0; i < 2; ++i) {
      const int Lb = w * 2048 + i * 1024 + lane * 16;
      gload_lds16(Kg + Lb, sKb + Lb);
    }
    // V: load coalesced, write transposed [d][s]
    const unsigned short* Vg = Vb + ((size_t)bh * 1024 + kt * 64) * 64;
#pragma unroll
    for (int j = 0; j < 2; ++j) {
      const int e = tid + j * 256;        // vec8 index 0..511
      const int s = e >> 3, d0 = (e & 7) * 8;
      short8 vv = *(const short8*)(Vg + s * 64 + d0);
#pragma unroll
      for (int q = 0; q < 8; ++q) sV[(d0 + q) * 72 + s] = (unsigned short)vv[q];
    }
    __syncthreads();  // staging visible

    // S = Q K^T  (wave w: q rows w*16..+15, all 64 k cols)
    f32x4 accS[4];
#pragma unroll
    for (int nt = 0; nt < 4; ++nt) accS[nt] = (f32x4){0.f, 0.f, 0.f, 0.f};
#pragma unroll
    for (int kk = 0; kk < 2; ++kk) {
      short8 aq = *(const short8*)(sQb + (w * 16 + ln) * 128 + kk * 64 + quad * 16);
#pragma unroll
      for (int nt = 0; nt < 4; ++nt) {
        short8 bk = *(const short8*)(sKb + (nt * 16 + ln) * 128 + kk * 64 + quad * 16);
        accS[nt] = __builtin_amdgcn_mfma_f32_16x16x32_bf16(aq, bk, accS[nt], 0, 0, 0);
      }
    }

    // online softmax; C-layout row = quad*4+r, col = nt*16+ln
#pragma unroll
    for (int r = 0; r < 4; ++r) {
      float tmax = fmaxf(fmaxf(accS[0][r], accS[1][r]), fmaxf(accS[2][r], accS[3][r]));
      tmax = fmaxf(tmax, __shfl_xor(tmax, 1, 16));
      tmax = fmaxf(tmax, __shfl_xor(tmax, 2, 16));
      tmax = fmaxf(tmax, __shfl_xor(tmax, 4, 16));
      tmax = fmaxf(tmax, __shfl_xor(tmax, 8, 16));
      const float mnew = fmaxf(mrow[r], tmax);
      const float alpha = __expf(mrow[r] - mnew);
      mrow[r] = mnew;
      float psum = 0.f;
#pragma unroll
      for (int nt = 0; nt < 4; ++nt) {
        const float p = __expf(accS[nt][r] - mnew);
        const unsigned short pb = f2bf(p);
        psum += bf2f(pb);  // l matches rounded P exactly
        sP[(w * 16 + quad * 4 + r) * 72 + nt * 16 + ln] = pb;
      }
      psum += __shfl_xor(psum, 1, 16);
      psum += __shfl_xor(psum, 2, 16);
      psum += __shfl_xor(psum, 4, 16);
      psum += __shfl_xor(psum, 8, 16);
      lrow[r] = lrow[r] * alpha + psum;
#pragma unroll
      for (int nt = 0; nt < 4; ++nt) accO[nt][r] *= alpha;
    }

    // O += P V   (A = P from LDS in A-layout; B = V^T rows are d, contiguous in k)
#pragma unroll
    for (int kk = 0; kk < 2; ++kk) {
      short8 ap = *(const short8*)(sPb + (w * 16 + ln) * 144 + kk * 64 + quad * 16);
#pragma unroll
      for (int nt = 0; nt < 4; ++nt) {
        short8 bv = *(const short8*)(sVb + (nt * 16 + ln) * 144 + kk * 64 + quad * 16);
        accO[nt] = __builtin_amdgcn_mfma_f32_16x16x32_bf16(ap, bv, accO[nt], 0, 0, 0);
      }
    }
  }

  // epilogue: ctx[b][s][h*64+d] bf16
#pragma unroll
  for (int r = 0; r < 4; ++r) {
    const float inv = 1.0f / lrow[r];
    const int s = qt * 64 + w * 16 + quad * 4 + r;
#pragma unroll
    for (int nt = 0; nt < 4; ++nt) {
      const int d = nt * 16 + ln;
      ctx[((size_t)(b * 1024 + s)) * 1024 + h * 64 + d] = f2bf(accO[nt][r] * inv);
    }
  }
}

// ---------- launch ----------
extern "C" void kernel_launch(void* const* d_in, const int* in_sizes, int n_in,
                              void* d_out, int out_size, void* d_ws, size_t ws_size,
                              hipStream_t stream) {
  const float* hs  = (const float*)d_in[0];
  const float* Wq  = (const float*)d_in[1];
  const float* bq  = (const float*)d_in[2];
  const float* LMq = (const float*)d_in[3];
  const float* RMq = (const float*)d_in[4];
  const float* Fq  = (const float*)d_in[5];
  const float* Wk  = (const float*)d_in[6];
  const float* bk  = (const float*)d_in[7];
  const float* LMk = (const float*)d_in[8];
  const float* RMk = (const float*)d_in[9];
  const float* Fk  = (const float*)d_in[10];
  const float* Wv  = (const float*)d_in[11];
  const float* bv  = (const float*)d_in[12];
  const float* LMv = (const float*)d_in[13];
  const float* RMv = (const float*)d_in[14];
  const float* Fv  = (const float*)d_in[15];
  const float* Wo  = (const float*)d_in[16];
  const float* bo  = (const float*)d_in[17];
  const float* LMo = (const float*)d_in[18];
  const float* RMo = (const float*)d_in[19];
  const float* Fo  = (const float*)d_in[20];
  // d_in[21] = task (always 0 branch in reference)

  // workspace layout (all 16B aligned)
  char* p = (char*)d_ws;
  unsigned short* xbf  = (unsigned short*)p; p += (size_t)16384 * 1024 * 2;   // 33.5 MB
  unsigned short* Wqkv = (unsigned short*)p; p += (size_t)3072 * 1024 * 2;    // 6.3 MB
  unsigned short* Wob  = (unsigned short*)p; p += (size_t)1024 * 1024 * 2;    // 2 MB
  float* bqkv = (float*)p; p += 3072 * 4;
  float* bob  = (float*)p; p += 1024 * 4;
  unsigned short* qkv = (unsigned short*)p; p += (size_t)3 * 16777216 * 2;    // 100.6 MB
  unsigned short* ctx = (unsigned short*)p; p += (size_t)16777216 * 2;        // 33.5 MB

  const float qscale = 0.125f;  // 1/sqrt(64) folded into q weights+bias

  cast_x<<<16384, 256, 0, stream>>>(hs, xbf, 16777216 / 4);
  prep_weights<<<1024, 256, 0, stream>>>(Wq, bq, LMq, RMq, Fq, qscale, Wqkv, bqkv);
  prep_weights<<<1024, 256, 0, stream>>>(Wk, bk, LMk, RMk, Fk, 1.0f, Wqkv + 1024 * 1024, bqkv + 1024);
  prep_weights<<<1024, 256, 0, stream>>>(Wv, bv, LMv, RMv, Fv, 1.0f, Wqkv + 2 * 1024 * 1024, bqkv + 2048);
  prep_weights<<<1024, 256, 0, stream>>>(Wo, bo, LMo, RMo, Fo, 1.0f, Wob, bob);

  gemm_bt<0><<<dim3(128, 24), 256, 0, stream>>>(xbf, Wqkv, bqkv, (void*)qkv, 16384, 3072, 1024);

  attn<<<dim3(16, 256), 256, 0, stream>>>(qkv, qkv + 16777216, qkv + 2 * 16777216, ctx);

  gemm_bt<1><<<dim3(128, 8), 256, 0, stream>>>(ctx, Wob, bob, d_out, 16384, 1024, 1024);
}

// Round 2
// 609.356 us; speedup vs baseline: 1.2651x; 1.2651x over previous
//
#include <hip/hip_runtime.h>
#include <cstdint>
#include <cstddef>

typedef short short8 __attribute__((ext_vector_type(8)));
typedef float f32x4 __attribute__((ext_vector_type(4)));
typedef unsigned short us4 __attribute__((ext_vector_type(4)));

// ---------- helpers ----------
__device__ __forceinline__ unsigned short f2bf(float f) {
  unsigned int u = __float_as_uint(f);
  unsigned int r = (u + 0x7fffu + ((u >> 16) & 1u)) >> 16;  // RNE
  return (unsigned short)r;
}
__device__ __forceinline__ float bf2f(unsigned short s) {
  return __uint_as_float(((unsigned int)s) << 16);
}
// async global->LDS, 16B per lane. LDS dest = wave-uniform base + lane*16.
__device__ __forceinline__ void gload_lds16(const void* g, void* l) {
  auto gp = reinterpret_cast<const __attribute__((address_space(1))) char*>(
      reinterpret_cast<uintptr_t>(g));
  auto lp = reinterpret_cast<__attribute__((address_space(3))) char*>(
      reinterpret_cast<uintptr_t>(l));
  __builtin_amdgcn_global_load_lds(gp, lp, 16, 0, 0);
}

// ---------- weight reconstruction: w' = (LM@RM + W) * F * scale (bf16), b' = b*F*scale ----------
__global__ __launch_bounds__(256) void prep_weights(
    const float* __restrict__ W, const float* __restrict__ bias,
    const float* __restrict__ LM, const float* __restrict__ RM,
    const float* __restrict__ F, float scale,
    unsigned short* __restrict__ Wout, float* __restrict__ bout) {
  const int o = blockIdx.x;      // output row 0..1023
  const int tid = threadIdx.x;   // 256
  __shared__ float lm[64];
  if (tid < 64) lm[tid] = LM[o * 64 + tid];
  __syncthreads();
  const float f = F[o] * scale;
#pragma unroll
  for (int j = 0; j < 4; ++j) {
    const int i = tid + j * 256;
    float acc = W[o * 1024 + i];
#pragma unroll 16
    for (int k = 0; k < 64; ++k) acc = fmaf(lm[k], RM[k * 1024 + i], acc);
    Wout[o * 1024 + i] = f2bf(acc * f);
  }
  if (tid == 0) bout[o] = bias[o] * f;
}

// ---------- f32 -> bf16 cast ----------
__global__ __launch_bounds__(256) void cast_x(const float* __restrict__ x,
                                              unsigned short* __restrict__ y, int n4) {
  const int i = blockIdx.x * 256 + threadIdx.x;
  if (i >= n4) return;
  f32x4 v = *(const f32x4*)(x + (size_t)i * 4);
  us4 o;
  o[0] = f2bf(v[0]); o[1] = f2bf(v[1]); o[2] = f2bf(v[2]); o[3] = f2bf(v[3]);
  *(us4*)(y + (size_t)i * 4) = o;
}

// ---------- GEMM: C[m][n] = sum_k A[m][k]*Bw[n][k] + bias[n] ----------
// 128x128 block tile, BK=64, 4 waves each 64x64 (4x4 of 16x16x32 mfma).
// MODE 0: scatter to qkv bf16: q,k -> [bh][s][d]; v -> TRANSPOSED [bh][d][s].
// MODE 1: f32 row-major out.
template <int MODE>
__global__ __launch_bounds__(256) void gemm_bt(const unsigned short* __restrict__ A,
                                               const unsigned short* __restrict__ Bw,
                                               const float* __restrict__ bias,
                                               void* __restrict__ Cout,
                                               int M, int N, int K) {
  __shared__ unsigned short sA[128 * 64];
  __shared__ unsigned short sB[128 * 64];
  const int tid = threadIdx.x;
  const int w = tid >> 6;
  const int lane = tid & 63;
  const int quad = lane >> 4;
  const int ln = lane & 15;
  const int bm = blockIdx.x, bn = blockIdx.y;
  const int wm = w >> 1, wn = w & 1;

  f32x4 acc[4][4];
#pragma unroll
  for (int a = 0; a < 4; ++a)
#pragma unroll
    for (int b = 0; b < 4; ++b) acc[a][b] = (f32x4){0.f, 0.f, 0.f, 0.f};

  const size_t Kb = (size_t)K * 2;
  const char* Agb = (const char*)A + (size_t)bm * 128 * Kb;
  const char* Bgb = (const char*)Bw + (size_t)bn * 128 * Kb;
  char* sAb = (char*)sA;
  char* sBb = (char*)sB;

  for (int k0 = 0; k0 < K; k0 += 64) {
    __syncthreads();  // LDS safe to overwrite
#pragma unroll
    for (int i = 0; i < 4; ++i) {
      const int Lb = w * 4096 + i * 1024 + lane * 16;  // linear byte in tile
      const int r = Lb >> 7;                           // tile row (128B rows)
      const int cb = Lb & 127;                         // byte in row
      gload_lds16(Agb + (size_t)r * Kb + (size_t)k0 * 2 + cb, sAb + Lb);
      gload_lds16(Bgb + (size_t)r * Kb + (size_t)k0 * 2 + cb, sBb + Lb);
    }
    __syncthreads();  // staging visible
#pragma unroll
    for (int kk = 0; kk < 2; ++kk) {
      short8 af[4], bfv[4];
#pragma unroll
      for (int t = 0; t < 4; ++t) {
        af[t]  = *(const short8*)(sAb + (wm * 64 + t * 16 + ln) * 128 + kk * 64 + quad * 16);
        bfv[t] = *(const short8*)(sBb + (wn * 64 + t * 16 + ln) * 128 + kk * 64 + quad * 16);
      }
#pragma unroll
      for (int mt = 0; mt < 4; ++mt)
#pragma unroll
        for (int nt = 0; nt < 4; ++nt)
          acc[mt][nt] = __builtin_amdgcn_mfma_f32_16x16x32_bf16(af[mt], bfv[nt], acc[mt][nt], 0, 0, 0);
    }
  }

  // epilogue. C/D layout: col = ln, row = quad*4 + reg (measured m89/m91)
  if (MODE == 0) {
    unsigned short* out = (unsigned short*)Cout;
#pragma unroll
    for (int mt = 0; mt < 4; ++mt) {
#pragma unroll
      for (int nt = 0; nt < 4; ++nt) {
        const int gn = bn * 128 + wn * 64 + nt * 16 + ln;
        const float bv = bias[gn];
        const int pidx = gn >> 10, rem = gn & 1023;
        const int hh = rem >> 6, dd = rem & 63;
        const int gm0 = bm * 128 + wm * 64 + mt * 16 + quad * 4;
        const int bb = gm0 >> 10, ss0 = gm0 & 1023;
        if (pidx < 2) {
          // q,k: [p][b][h][s][d]
#pragma unroll
          for (int r = 0; r < 4; ++r) {
            const size_t off = ((((size_t)pidx * 16 + bb) * 16 + hh) * 1024 + (ss0 + r)) * 64 + dd;
            out[off] = f2bf(acc[mt][nt][r] + bv);
          }
        } else {
          // v: transposed [b][h][d][s]; r -> consecutive s -> one 8B store
          us4 pk;
#pragma unroll
          for (int r = 0; r < 4; ++r) pk[r] = f2bf(acc[mt][nt][r] + bv);
          const size_t off = (size_t)2 * 16777216 +
                             (((size_t)(bb * 16 + hh) * 64 + dd) * 1024 + ss0);
          *(us4*)(out + off) = pk;
        }
      }
    }
  } else {
    float* out = (float*)Cout;
#pragma unroll
    for (int mt = 0; mt < 4; ++mt) {
#pragma unroll
      for (int nt = 0; nt < 4; ++nt) {
        const int gn = bn * 128 + wn * 64 + nt * 16 + ln;
        const float bv = bias[gn];
#pragma unroll
        for (int r = 0; r < 4; ++r) {
          const int gm = bm * 128 + wm * 64 + mt * 16 + quad * 4 + r;
          out[(size_t)gm * N + gn] = acc[mt][nt][r] + bv;
        }
      }
    }
  }
}

// ---------- flash attention, S^T formulation ----------
// One block per (bh, 64-row q tile). q pre-scaled by 1/sqrt(64).
// Q,K layout [bh][s][d]; V layout TRANSPOSED [bh][d][s]. All bf16, S=1024, d=64.
// Computes S^T = K Q^T so each lane owns one q column (q = w*16+ln) with
// 4-consecutive-kv register groups -> vectorized P write + cheap reductions.
__global__ __launch_bounds__(256) void attn(const unsigned short* __restrict__ Qb,
                                            const unsigned short* __restrict__ Kb_,
                                            const unsigned short* __restrict__ VTb,
                                            unsigned short* __restrict__ ctx) {
  __shared__ unsigned short sK[64 * 64];   // [kv][d], 128B rows
  __shared__ unsigned short sVT[64 * 64];  // [d][kv], 128B rows
  __shared__ unsigned short sP[64 * 72];   // [q][kv], 144B rows (pad 8 shorts)
  const int tid = threadIdx.x;
  const int w = tid >> 6, lane = tid & 63, quad = lane >> 4, ln = lane & 15;
  const int qt = blockIdx.x, bh = blockIdx.y;
  const int b = bh >> 4, h = bh & 15;

  char* sKb = (char*)sK;
  char* sVb = (char*)sVT;
  char* sPb = (char*)sP;

  // Q fragments (B-operand) direct from global, loop-invariant.
  // B-layout: n=ln -> q = w*16+ln; k = kk*32 + quad*8 + j
  const unsigned short* Qg = Qb + ((size_t)bh * 1024 + (size_t)qt * 64 + w * 16 + ln) * 64;
  const short8 bq0 = *(const short8*)(Qg + quad * 8);
  const short8 bq1 = *(const short8*)(Qg + 32 + quad * 8);

  f32x4 accO[4];
#pragma unroll
  for (int nt = 0; nt < 4; ++nt) accO[nt] = (f32x4){0.f, 0.f, 0.f, 0.f};
  float mrun = -3e38f, lrun = 0.f;

  for (int kt = 0; kt < 16; ++kt) {
    __syncthreads();  // previous tile's compute done, LDS safe to overwrite
    const char* Kg = (const char*)(Kb_ + ((size_t)bh * 1024 + (size_t)kt * 64) * 64);
    const char* Vg = (const char*)(VTb + (size_t)bh * 65536 + (size_t)kt * 64);
#pragma unroll
    for (int i = 0; i < 2; ++i) {
      const int Lb = w * 2048 + i * 1024 + lane * 16;
      const int r = Lb >> 7, cb = Lb & 127;
      gload_lds16(Kg + Lb, sKb + Lb);                      // K rows contiguous
      gload_lds16(Vg + (size_t)r * 2048 + cb, sVb + Lb);   // V^T rows stride 2048B
    }
    __syncthreads();  // staging visible

    // S^T = K Q^T : A = K (m=ln -> kv), B = Q. accS[mt]: kv tile mt*16..+15
    f32x4 accS[4];
#pragma unroll
    for (int mt = 0; mt < 4; ++mt) accS[mt] = (f32x4){0.f, 0.f, 0.f, 0.f};
#pragma unroll
    for (int mt = 0; mt < 4; ++mt) {
      const short8 ak0 = *(const short8*)(sKb + (mt * 16 + ln) * 128 + quad * 16);
      accS[mt] = __builtin_amdgcn_mfma_f32_16x16x32_bf16(ak0, bq0, accS[mt], 0, 0, 0);
    }
#pragma unroll
    for (int mt = 0; mt < 4; ++mt) {
      const short8 ak1 = *(const short8*)(sKb + (mt * 16 + ln) * 128 + 64 + quad * 16);
      accS[mt] = __builtin_amdgcn_mfma_f32_16x16x32_bf16(ak1, bq1, accS[mt], 0, 0, 0);
    }

    // online softmax over kv. Lane holds S[q=w*16+ln][kv = mt*16 + quad*4 + r].
    float tmax = -3e38f;
#pragma unroll
    for (int mt = 0; mt < 4; ++mt)
#pragma unroll
      for (int r = 0; r < 4; ++r) tmax = fmaxf(tmax, accS[mt][r]);
    tmax = fmaxf(tmax, __shfl_xor(tmax, 16));
    tmax = fmaxf(tmax, __shfl_xor(tmax, 32));
    const float mnew = fmaxf(mrun, tmax);
    const float alpha = __expf(mrun - mnew);
    mrun = mnew;
    float psum = 0.f;
#pragma unroll
    for (int mt = 0; mt < 4; ++mt) {
      us4 pk;
#pragma unroll
      for (int r = 0; r < 4; ++r) {
        const float p = __expf(accS[mt][r] - mnew);
        const unsigned short pb = f2bf(p);
        psum += bf2f(pb);  // l matches rounded P exactly
        pk[r] = pb;
      }
      *(us4*)(sP + (w * 16 + ln) * 72 + mt * 16 + quad * 4) = pk;  // 8B write
    }
    psum += __shfl_xor(psum, 16);
    psum += __shfl_xor(psum, 32);
    lrun = lrun * alpha + psum;
    // rescale O (C-layout rows are q_local = quad*4+r; state lives at lane ln=q_local)
#pragma unroll
    for (int r = 0; r < 4; ++r) {
      const float ar = __shfl(alpha, quad * 4 + r);
#pragma unroll
      for (int nt = 0; nt < 4; ++nt) accO[nt][r] *= ar;
    }

    // O += P V : A = P[q][kv] from sP (m=ln -> q, wave-local rows), B = V^T rows d
#pragma unroll
    for (int kk = 0; kk < 2; ++kk) {
      const short8 ap = *(const short8*)(sPb + (w * 16 + ln) * 144 + kk * 64 + quad * 16);
#pragma unroll
      for (int nt = 0; nt < 4; ++nt) {
        const short8 bv = *(const short8*)(sVb + (nt * 16 + ln) * 128 + kk * 64 + quad * 16);
        accO[nt] = __builtin_amdgcn_mfma_f32_16x16x32_bf16(ap, bv, accO[nt], 0, 0, 0);
      }
    }
  }

  // epilogue: ctx[b][s][h*64+d] bf16
  const float inv = 1.0f / lrun;
#pragma unroll
  for (int r = 0; r < 4; ++r) {
    const float ivr = __shfl(inv, quad * 4 + r);
    const int s = qt * 64 + w * 16 + quad * 4 + r;
#pragma unroll
    for (int nt = 0; nt < 4; ++nt) {
      const int d = nt * 16 + ln;
      ctx[((size_t)(b * 1024 + s)) * 1024 + h * 64 + d] = f2bf(accO[nt][r] * ivr);
    }
  }
}

// ---------- launch ----------
extern "C" void kernel_launch(void* const* d_in, const int* in_sizes, int n_in,
                              void* d_out, int out_size, void* d_ws, size_t ws_size,
                              hipStream_t stream) {
  const float* hs  = (const float*)d_in[0];
  const float* Wq  = (const float*)d_in[1];
  const float* bq  = (const float*)d_in[2];
  const float* LMq = (const float*)d_in[3];
  const float* RMq = (const float*)d_in[4];
  const float* Fq  = (const float*)d_in[5];
  const float* Wk  = (const float*)d_in[6];
  const float* bk  = (const float*)d_in[7];
  const float* LMk = (const float*)d_in[8];
  const float* RMk = (const float*)d_in[9];
  const float* Fk  = (const float*)d_in[10];
  const float* Wv  = (const float*)d_in[11];
  const float* bv  = (const float*)d_in[12];
  const float* LMv = (const float*)d_in[13];
  const float* RMv = (const float*)d_in[14];
  const float* Fv  = (const float*)d_in[15];
  const float* Wo  = (const float*)d_in[16];
  const float* bo  = (const float*)d_in[17];
  const float* LMo = (const float*)d_in[18];
  const float* RMo = (const float*)d_in[19];
  const float* Fo  = (const float*)d_in[20];
  // d_in[21] = task (always 0 branch in reference)

  // workspace layout (all 16B aligned)
  char* p = (char*)d_ws;
  unsigned short* xbf  = (unsigned short*)p; p += (size_t)16384 * 1024 * 2;   // 33.5 MB
  unsigned short* Wqkv = (unsigned short*)p; p += (size_t)3072 * 1024 * 2;    // 6.3 MB
  unsigned short* Wob  = (unsigned short*)p; p += (size_t)1024 * 1024 * 2;    // 2 MB
  float* bqkv = (float*)p; p += 3072 * 4;
  float* bob  = (float*)p; p += 1024 * 4;
  unsigned short* qkv = (unsigned short*)p; p += (size_t)3 * 16777216 * 2;    // 100.6 MB
  unsigned short* ctx = (unsigned short*)p; p += (size_t)16777216 * 2;        // 33.5 MB

  const float qscale = 0.125f;  // 1/sqrt(64) folded into q weights+bias

  cast_x<<<16384, 256, 0, stream>>>(hs, xbf, 16777216 / 4);
  prep_weights<<<1024, 256, 0, stream>>>(Wq, bq, LMq, RMq, Fq, qscale, Wqkv, bqkv);
  prep_weights<<<1024, 256, 0, stream>>>(Wk, bk, LMk, RMk, Fk, 1.0f, Wqkv + 1024 * 1024, bqkv + 1024);
  prep_weights<<<1024, 256, 0, stream>>>(Wv, bv, LMv, RMv, Fv, 1.0f, Wqkv + 2 * 1024 * 1024, bqkv + 2048);
  prep_weights<<<1024, 256, 0, stream>>>(Wo, bo, LMo, RMo, Fo, 1.0f, Wob, bob);

  gemm_bt<0><<<dim3(128, 24), 256, 0, stream>>>(xbf, Wqkv, bqkv, (void*)qkv, 16384, 3072, 1024);

  attn<<<dim3(16, 256), 256, 0, stream>>>(qkv, qkv + 16777216, qkv + 2 * 16777216, ctx);

  gemm_bt<1><<<dim3(128, 8), 256, 0, stream>>>(ctx, Wob, bob, d_out, 16384, 1024, 1024);
}

// Round 4
// 522.209 us; speedup vs baseline: 1.4762x; 1.1669x over previous
//
#include <hip/hip_runtime.h>
#include <cstdint>
#include <cstddef>

typedef short short8 __attribute__((ext_vector_type(8)));
typedef float f32x4 __attribute__((ext_vector_type(4)));
typedef unsigned short us4 __attribute__((ext_vector_type(4)));
typedef unsigned int u32x2 __attribute__((ext_vector_type(2)));

// ---------- helpers ----------
__device__ __forceinline__ unsigned short f2bf(float f) {
  unsigned int u = __float_as_uint(f);
  unsigned int r = (u + 0x7fffu + ((u >> 16) & 1u)) >> 16;  // RNE
  return (unsigned short)r;
}
// v_exp_f32: D = 2^S0 (use builtin; __exp2f collides with glibc math.h here)
__device__ __forceinline__ float exp2_fast(float x) {
  return __builtin_amdgcn_exp2f(x);
}
// gfx950 packed f32->bf16 RNE convert: D[15:0]=bf16(a), D[31:16]=bf16(b)
__device__ __forceinline__ unsigned int cvt_pk_bf16(float a, float b) {
  unsigned int d;
  asm("v_cvt_pk_bf16_f32 %0, %1, %2" : "=v"(d) : "v"(a), "v"(b));
  return d;
}
// async global->LDS, 16B per lane. LDS dest = wave-uniform base + lane*16.
__device__ __forceinline__ void gload_lds16(const void* g, void* l) {
  auto gp = reinterpret_cast<const __attribute__((address_space(1))) char*>(
      reinterpret_cast<uintptr_t>(g));
  auto lp = reinterpret_cast<__attribute__((address_space(3))) char*>(
      reinterpret_cast<uintptr_t>(l));
  __builtin_amdgcn_global_load_lds(gp, lp, 16, 0, 0);
}

// ---------- weight reconstruction: w' = (LM@RM + W) * F * scale (bf16), b' = b*F*scale ----------
__global__ __launch_bounds__(256) void prep_weights(
    const float* __restrict__ W, const float* __restrict__ bias,
    const float* __restrict__ LM, const float* __restrict__ RM,
    const float* __restrict__ F, float scale,
    unsigned short* __restrict__ Wout, float* __restrict__ bout) {
  const int o = blockIdx.x;      // output row 0..1023
  const int tid = threadIdx.x;   // 256
  __shared__ float lm[64];
  if (tid < 64) lm[tid] = LM[o * 64 + tid];
  __syncthreads();
  const float f = F[o] * scale;
#pragma unroll
  for (int j = 0; j < 4; ++j) {
    const int i = tid + j * 256;
    float acc = W[o * 1024 + i];
#pragma unroll 16
    for (int k = 0; k < 64; ++k) acc = fmaf(lm[k], RM[k * 1024 + i], acc);
    Wout[o * 1024 + i] = f2bf(acc * f);
  }
  if (tid == 0) bout[o] = bias[o] * f;
}

// ---------- f32 -> bf16 cast ----------
__global__ __launch_bounds__(256) void cast_x(const float* __restrict__ x,
                                              unsigned short* __restrict__ y, int n4) {
  const int i = blockIdx.x * 256 + threadIdx.x;
  if (i >= n4) return;
  f32x4 v = *(const f32x4*)(x + (size_t)i * 4);
  us4 o;
  o[0] = f2bf(v[0]); o[1] = f2bf(v[1]); o[2] = f2bf(v[2]); o[3] = f2bf(v[3]);
  *(us4*)(y + (size_t)i * 4) = o;
}

// ---------- GEMM: C[m][n] = sum_k A[m][k]*Bw[n][k] + bias[n] ----------
// 128x128 block tile, BK=64, 4 waves each 64x64 (4x4 of 16x16x32 mfma).
// LDS layout XOR-swizzled: 16B chunk c of row r stored at chunk position c^(r&7)
// (swizzle applied on the GLOBAL address at staging; reads use swizzled chunk).
// MODE 0: scatter to qkv bf16: q,k -> [bh][s][d]; v -> TRANSPOSED [bh][d][s].
// MODE 1: f32 row-major out.
template <int MODE>
__global__ __launch_bounds__(256) void gemm_bt(const unsigned short* __restrict__ A,
                                               const unsigned short* __restrict__ Bw,
                                               const float* __restrict__ bias,
                                               void* __restrict__ Cout,
                                               int M, int N, int K) {
  __shared__ unsigned short sA[128 * 64];
  __shared__ unsigned short sB[128 * 64];
  const int tid = threadIdx.x;
  const int w = tid >> 6;
  const int lane = tid & 63;
  const int quad = lane >> 4;
  const int ln = lane & 15;
  const int bm = blockIdx.x, bn = blockIdx.y;
  const int wm = w >> 1, wn = w & 1;

  f32x4 acc[4][4];
#pragma unroll
  for (int a = 0; a < 4; ++a)
#pragma unroll
    for (int b = 0; b < 4; ++b) acc[a][b] = (f32x4){0.f, 0.f, 0.f, 0.f};

  const size_t Kb = (size_t)K * 2;
  const char* Agb = (const char*)A + (size_t)bm * 128 * Kb;
  const char* Bgb = (const char*)Bw + (size_t)bn * 128 * Kb;
  char* sAb = (char*)sA;
  char* sBb = (char*)sB;
  const int sw = ln & 7;

  for (int k0 = 0; k0 < K; k0 += 64) {
    __syncthreads();  // LDS safe to overwrite
#pragma unroll
    for (int i = 0; i < 4; ++i) {
      const int Lb = w * 4096 + i * 1024 + lane * 16;  // linear byte in tile
      const int r = Lb >> 7;                           // tile row (128B rows)
      const int c = (Lb >> 4) & 7;                     // LDS chunk slot
      const int cb = ((c ^ (r & 7)) * 16);             // global chunk (unswizzle)
      gload_lds16(Agb + (size_t)r * Kb + (size_t)k0 * 2 + cb, sAb + Lb);
      gload_lds16(Bgb + (size_t)r * Kb + (size_t)k0 * 2 + cb, sBb + Lb);
    }
    __syncthreads();  // staging visible
#pragma unroll
    for (int kk = 0; kk < 2; ++kk) {
      short8 af[4], bfv[4];
#pragma unroll
      for (int t = 0; t < 4; ++t) {
        const int ch = ((kk * 4 + quad) ^ sw) * 16;
        af[t]  = *(const short8*)(sAb + (wm * 64 + t * 16 + ln) * 128 + ch);
        bfv[t] = *(const short8*)(sBb + (wn * 64 + t * 16 + ln) * 128 + ch);
      }
#pragma unroll
      for (int mt = 0; mt < 4; ++mt)
#pragma unroll
        for (int nt = 0; nt < 4; ++nt)
          acc[mt][nt] = __builtin_amdgcn_mfma_f32_16x16x32_bf16(af[mt], bfv[nt], acc[mt][nt], 0, 0, 0);
    }
  }

  // epilogue. C/D layout: col = ln, row = quad*4 + reg (measured m89/m91)
  if (MODE == 0) {
    unsigned short* out = (unsigned short*)Cout;
#pragma unroll
    for (int mt = 0; mt < 4; ++mt) {
#pragma unroll
      for (int nt = 0; nt < 4; ++nt) {
        const int gn = bn * 128 + wn * 64 + nt * 16 + ln;
        const float bv = bias[gn];
        const int pidx = gn >> 10, rem = gn & 1023;
        const int hh = rem >> 6, dd = rem & 63;
        const int gm0 = bm * 128 + wm * 64 + mt * 16 + quad * 4;
        const int bb = gm0 >> 10, ss0 = gm0 & 1023;
        if (pidx < 2) {
          // q,k: [p][b][h][s][d]
#pragma unroll
          for (int r = 0; r < 4; ++r) {
            const size_t off = ((((size_t)pidx * 16 + bb) * 16 + hh) * 1024 + (ss0 + r)) * 64 + dd;
            out[off] = f2bf(acc[mt][nt][r] + bv);
          }
        } else {
          // v: transposed [b][h][d][s]; r -> consecutive s -> one 8B store
          us4 pk;
#pragma unroll
          for (int r = 0; r < 4; ++r) pk[r] = f2bf(acc[mt][nt][r] + bv);
          const size_t off = (size_t)2 * 16777216 +
                             (((size_t)(bb * 16 + hh) * 64 + dd) * 1024 + ss0);
          *(us4*)(out + off) = pk;
        }
      }
    }
  } else {
    float* out = (float*)Cout;
#pragma unroll
    for (int mt = 0; mt < 4; ++mt) {
#pragma unroll
      for (int nt = 0; nt < 4; ++nt) {
        const int gn = bn * 128 + wn * 64 + nt * 16 + ln;
        const float bv = bias[gn];
#pragma unroll
        for (int r = 0; r < 4; ++r) {
          const int gm = bm * 128 + wm * 64 + mt * 16 + quad * 4 + r;
          out[(size_t)gm * N + gn] = acc[mt][nt][r] + bv;
        }
      }
    }
  }
}

// ---------- flash attention, S^T formulation ----------
// One block per (bh, 64-row q tile). q pre-scaled by log2(e)/sqrt(64) -> exp2 softmax.
// Q,K layout [bh][s][d]; V layout TRANSPOSED [bh][d][s]. All bf16, S=1024, d=64.
// sK/sVT XOR-swizzled like the GEMM tiles.
__global__ __launch_bounds__(256) void attn(const unsigned short* __restrict__ Qb,
                                            const unsigned short* __restrict__ Kb_,
                                            const unsigned short* __restrict__ VTb,
                                            unsigned short* __restrict__ ctx) {
  __shared__ unsigned short sK[64 * 64];   // [kv][d], 128B rows, swizzled chunks
  __shared__ unsigned short sVT[64 * 64];  // [d][kv], 128B rows, swizzled chunks
  __shared__ unsigned short sP[64 * 72];   // [q][kv], 144B rows (pad 8 shorts)
  const int tid = threadIdx.x;
  const int w = tid >> 6, lane = tid & 63, quad = lane >> 4, ln = lane & 15;
  const int qt = blockIdx.x, bh = blockIdx.y;
  const int b = bh >> 4, h = bh & 15;

  char* sKb = (char*)sK;
  char* sVb = (char*)sVT;
  char* sPb = (char*)sP;
  const int sw = ln & 7;

  // Q fragments (B-operand) direct from global, loop-invariant.
  const unsigned short* Qg = Qb + ((size_t)bh * 1024 + (size_t)qt * 64 + w * 16 + ln) * 64;
  const short8 bq0 = *(const short8*)(Qg + quad * 8);
  const short8 bq1 = *(const short8*)(Qg + 32 + quad * 8);

  f32x4 accO[4];
#pragma unroll
  for (int nt = 0; nt < 4; ++nt) accO[nt] = (f32x4){0.f, 0.f, 0.f, 0.f};
  float mrun = -3e38f, lrun = 0.f;

  for (int kt = 0; kt < 16; ++kt) {
    __syncthreads();  // previous tile's compute done, LDS safe to overwrite
    const char* Kg = (const char*)(Kb_ + ((size_t)bh * 1024 + (size_t)kt * 64) * 64);
    const char* Vg = (const char*)(VTb + (size_t)bh * 65536 + (size_t)kt * 64);
#pragma unroll
    for (int i = 0; i < 2; ++i) {
      const int Lb = w * 2048 + i * 1024 + lane * 16;
      const int r = Lb >> 7;
      const int c = (Lb >> 4) & 7;
      const int cb = ((c ^ (r & 7)) * 16);
      gload_lds16(Kg + (size_t)r * 128 + cb, sKb + Lb);    // K rows contiguous
      gload_lds16(Vg + (size_t)r * 2048 + cb, sVb + Lb);   // V^T rows stride 2048B
    }
    __syncthreads();  // staging visible

    // S^T = K Q^T : A = K (m=ln -> kv), B = Q. accS[mt]: kv tile mt*16..+15
    f32x4 accS[4];
#pragma unroll
    for (int mt = 0; mt < 4; ++mt) accS[mt] = (f32x4){0.f, 0.f, 0.f, 0.f};
#pragma unroll
    for (int mt = 0; mt < 4; ++mt) {
      const short8 ak0 = *(const short8*)(sKb + (mt * 16 + ln) * 128 + (quad ^ sw) * 16);
      accS[mt] = __builtin_amdgcn_mfma_f32_16x16x32_bf16(ak0, bq0, accS[mt], 0, 0, 0);
    }
#pragma unroll
    for (int mt = 0; mt < 4; ++mt) {
      const short8 ak1 = *(const short8*)(sKb + (mt * 16 + ln) * 128 + ((4 + quad) ^ sw) * 16);
      accS[mt] = __builtin_amdgcn_mfma_f32_16x16x32_bf16(ak1, bq1, accS[mt], 0, 0, 0);
    }

    // online softmax (base-2; q-logits pre-scaled by log2e).
    // Lane holds S[q=w*16+ln][kv = mt*16 + quad*4 + r].
    float tmax = -3e38f;
#pragma unroll
    for (int mt = 0; mt < 4; ++mt)
#pragma unroll
      for (int r = 0; r < 4; ++r) tmax = fmaxf(tmax, accS[mt][r]);
    tmax = fmaxf(tmax, __shfl_xor(tmax, 16));
    tmax = fmaxf(tmax, __shfl_xor(tmax, 32));
    const float mnew = fmaxf(mrun, tmax);
    const float alpha = exp2_fast(mrun - mnew);
    mrun = mnew;
    float psum = 0.f;
#pragma unroll
    for (int mt = 0; mt < 4; ++mt) {
      float p0 = exp2_fast(accS[mt][0] - mnew);
      float p1 = exp2_fast(accS[mt][1] - mnew);
      float p2 = exp2_fast(accS[mt][2] - mnew);
      float p3 = exp2_fast(accS[mt][3] - mnew);
      psum += (p0 + p1) + (p2 + p3);
      u32x2 pk;
      pk[0] = cvt_pk_bf16(p0, p1);
      pk[1] = cvt_pk_bf16(p2, p3);
      *(u32x2*)(sP + (w * 16 + ln) * 72 + mt * 16 + quad * 4) = pk;  // 8B write
    }
    psum += __shfl_xor(psum, 16);
    psum += __shfl_xor(psum, 32);
    lrun = lrun * alpha + psum;
    // rescale O (C-layout rows are q_local = quad*4+r; state lives at lane ln=q_local)
#pragma unroll
    for (int r = 0; r < 4; ++r) {
      const float ar = __shfl(alpha, quad * 4 + r);
#pragma unroll
      for (int nt = 0; nt < 4; ++nt) accO[nt][r] *= ar;
    }

    // O += P V : A = P[q][kv] from sP (m=ln -> q, wave-local rows), B = V^T rows d
#pragma unroll
    for (int kk = 0; kk < 2; ++kk) {
      const short8 ap = *(const short8*)(sPb + (w * 16 + ln) * 144 + kk * 64 + quad * 16);
#pragma unroll
      for (int nt = 0; nt < 4; ++nt) {
        const short8 bv = *(const short8*)(sVb + (nt * 16 + ln) * 128 + ((kk * 4 + quad) ^ sw) * 16);
        accO[nt] = __builtin_amdgcn_mfma_f32_16x16x32_bf16(ap, bv, accO[nt], 0, 0, 0);
      }
    }
  }

  // epilogue: ctx[b][s][h*64+d] bf16
  const float inv = 1.0f / lrun;
#pragma unroll
  for (int r = 0; r < 4; ++r) {
    const float ivr = __shfl(inv, quad * 4 + r);
    const int s = qt * 64 + w * 16 + quad * 4 + r;
#pragma unroll
    for (int nt = 0; nt < 4; ++nt) {
      const int d = nt * 16 + ln;
      ctx[((size_t)(b * 1024 + s)) * 1024 + h * 64 + d] = f2bf(accO[nt][r] * ivr);
    }
  }
}

// ---------- launch ----------
extern "C" void kernel_launch(void* const* d_in, const int* in_sizes, int n_in,
                              void* d_out, int out_size, void* d_ws, size_t ws_size,
                              hipStream_t stream) {
  const float* hs  = (const float*)d_in[0];
  const float* Wq  = (const float*)d_in[1];
  const float* bq  = (const float*)d_in[2];
  const float* LMq = (const float*)d_in[3];
  const float* RMq = (const float*)d_in[4];
  const float* Fq  = (const float*)d_in[5];
  const float* Wk  = (const float*)d_in[6];
  const float* bk  = (const float*)d_in[7];
  const float* LMk = (const float*)d_in[8];
  const float* RMk = (const float*)d_in[9];
  const float* Fk  = (const float*)d_in[10];
  const float* Wv  = (const float*)d_in[11];
  const float* bv  = (const float*)d_in[12];
  const float* LMv = (const float*)d_in[13];
  const float* RMv = (const float*)d_in[14];
  const float* Fv  = (const float*)d_in[15];
  const float* Wo  = (const float*)d_in[16];
  const float* bo  = (const float*)d_in[17];
  const float* LMo = (const float*)d_in[18];
  const float* RMo = (const float*)d_in[19];
  const float* Fo  = (const float*)d_in[20];
  // d_in[21] = task (always 0 branch in reference)

  // workspace layout (all 16B aligned)
  char* p = (char*)d_ws;
  unsigned short* xbf  = (unsigned short*)p; p += (size_t)16384 * 1024 * 2;   // 33.5 MB
  unsigned short* Wqkv = (unsigned short*)p; p += (size_t)3072 * 1024 * 2;    // 6.3 MB
  unsigned short* Wob  = (unsigned short*)p; p += (size_t)1024 * 1024 * 2;    // 2 MB
  float* bqkv = (float*)p; p += 3072 * 4;
  float* bob  = (float*)p; p += 1024 * 4;
  unsigned short* qkv = (unsigned short*)p; p += (size_t)3 * 16777216 * 2;    // 100.6 MB
  unsigned short* ctx = (unsigned short*)p; p += (size_t)16777216 * 2;        // 33.5 MB

  // 1/sqrt(64) * log2(e) folded into q weights+bias -> softmax in base 2
  const float qscale = 0.125f * 1.4426950408889634f;

  cast_x<<<16384, 256, 0, stream>>>(hs, xbf, 16777216 / 4);
  prep_weights<<<1024, 256, 0, stream>>>(Wq, bq, LMq, RMq, Fq, qscale, Wqkv, bqkv);
  prep_weights<<<1024, 256, 0, stream>>>(Wk, bk, LMk, RMk, Fk, 1.0f, Wqkv + 1024 * 1024, bqkv + 1024);
  prep_weights<<<1024, 256, 0, stream>>>(Wv, bv, LMv, RMv, Fv, 1.0f, Wqkv + 2 * 1024 * 1024, bqkv + 2048);
  prep_weights<<<1024, 256, 0, stream>>>(Wo, bo, LMo, RMo, Fo, 1.0f, Wob, bob);

  gemm_bt<0><<<dim3(128, 24), 256, 0, stream>>>(xbf, Wqkv, bqkv, (void*)qkv, 16384, 3072, 1024);

  attn<<<dim3(16, 256), 256, 0, stream>>>(qkv, qkv + 16777216, qkv + 2 * 16777216, ctx);

  gemm_bt<1><<<dim3(128, 8), 256, 0, stream>>>(ctx, Wob, bob, d_out, 16384, 1024, 1024);
}

// Round 6
// 514.492 us; speedup vs baseline: 1.4983x; 1.0150x over previous
//
#include <hip/hip_runtime.h>
#include <cstdint>
#include <cstddef>

typedef short short8 __attribute__((ext_vector_type(8)));
typedef float f32x4 __attribute__((ext_vector_type(4)));
typedef unsigned short us4 __attribute__((ext_vector_type(4)));

// ---------- helpers ----------
__device__ __forceinline__ unsigned short f2bf(float f) {
  unsigned int u = __float_as_uint(f);
  unsigned int r = (u + 0x7fffu + ((u >> 16) & 1u)) >> 16;  // RNE
  return (unsigned short)r;
}
// v_exp_f32: D = 2^S0 (builtin; __exp2f collides with glibc math.h here)
__device__ __forceinline__ float exp2_fast(float x) {
  return __builtin_amdgcn_exp2f(x);
}
// gfx950 packed f32->bf16 RNE convert: D[15:0]=bf16(a), D[31:16]=bf16(b)
__device__ __forceinline__ unsigned int cvt_pk_bf16(float a, float b) {
  unsigned int d;
  asm("v_cvt_pk_bf16_f32 %0, %1, %2" : "=v"(d) : "v"(a), "v"(b));
  return d;
}
// async global->LDS, 16B per lane. LDS dest = wave-uniform base + lane*16.
__device__ __forceinline__ void gload_lds16(const void* g, void* l) {
  auto gp = reinterpret_cast<const __attribute__((address_space(1))) char*>(
      reinterpret_cast<uintptr_t>(g));
  auto lp = reinterpret_cast<__attribute__((address_space(3))) char*>(
      reinterpret_cast<uintptr_t>(l));
  __builtin_amdgcn_global_load_lds(gp, lp, 16, 0, 0);
}

// ---------- weight reconstruction: w' = (LM@RM + W) * F * scale (bf16), b' = b*F*scale ----------
__global__ __launch_bounds__(256) void prep_weights(
    const float* __restrict__ W, const float* __restrict__ bias,
    const float* __restrict__ LM, const float* __restrict__ RM,
    const float* __restrict__ F, float scale,
    unsigned short* __restrict__ Wout, float* __restrict__ bout) {
  const int o = blockIdx.x;      // output row 0..1023
  const int tid = threadIdx.x;   // 256
  __shared__ float lm[64];
  if (tid < 64) lm[tid] = LM[o * 64 + tid];
  __syncthreads();
  const float f = F[o] * scale;
#pragma unroll
  for (int j = 0; j < 4; ++j) {
    const int i = tid + j * 256;
    float acc = W[o * 1024 + i];
#pragma unroll 16
    for (int k = 0; k < 64; ++k) acc = fmaf(lm[k], RM[k * 1024 + i], acc);
    Wout[o * 1024 + i] = f2bf(acc * f);
  }
  if (tid == 0) bout[o] = bias[o] * f;
}

// ---------- f32 -> bf16 cast ----------
__global__ __launch_bounds__(256) void cast_x(const float* __restrict__ x,
                                              unsigned short* __restrict__ y, int n4) {
  const int i = blockIdx.x * 256 + threadIdx.x;
  if (i >= n4) return;
  f32x4 v = *(const f32x4*)(x + (size_t)i * 4);
  us4 o;
  o[0] = f2bf(v[0]); o[1] = f2bf(v[1]); o[2] = f2bf(v[2]); o[3] = f2bf(v[3]);
  *(us4*)(y + (size_t)i * 4) = o;
}

// ---------- GEMM: C[m][n] = sum_k A[m][k]*Bw[n][k] + bias[n] ----------
// 128x128 block tile, BK=64, 4 waves each 64x64 (4x4 of 16x16x32 mfma).
// LDS XOR-swizzled: 16B chunk c of row r stored at chunk position c^(r&7).
// MODE 0: scatter to qkv bf16: q,k -> [bh][s][d]; v -> TRANSPOSED [bh][d][s].
// MODE 1: f32 row-major out.
template <int MODE>
__global__ __launch_bounds__(256) void gemm_bt(const unsigned short* __restrict__ A,
                                               const unsigned short* __restrict__ Bw,
                                               const float* __restrict__ bias,
                                               void* __restrict__ Cout,
                                               int M, int N, int K) {
  __shared__ unsigned short sA[128 * 64];
  __shared__ unsigned short sB[128 * 64];
  const int tid = threadIdx.x;
  const int w = tid >> 6;
  const int lane = tid & 63;
  const int quad = lane >> 4;
  const int ln = lane & 15;
  const int bm = blockIdx.x, bn = blockIdx.y;
  const int wm = w >> 1, wn = w & 1;

  f32x4 acc[4][4];
#pragma unroll
  for (int a = 0; a < 4; ++a)
#pragma unroll
    for (int b = 0; b < 4; ++b) acc[a][b] = (f32x4){0.f, 0.f, 0.f, 0.f};

  const size_t Kb = (size_t)K * 2;
  const char* Agb = (const char*)A + (size_t)bm * 128 * Kb;
  const char* Bgb = (const char*)Bw + (size_t)bn * 128 * Kb;
  char* sAb = (char*)sA;
  char* sBb = (char*)sB;
  const int sw = ln & 7;

  for (int k0 = 0; k0 < K; k0 += 64) {
    __syncthreads();  // LDS safe to overwrite
#pragma unroll
    for (int i = 0; i < 4; ++i) {
      const int Lb = w * 4096 + i * 1024 + lane * 16;  // linear byte in tile
      const int r = Lb >> 7;                           // tile row (128B rows)
      const int c = (Lb >> 4) & 7;                     // LDS chunk slot
      const int cb = ((c ^ (r & 7)) * 16);             // global chunk (unswizzle)
      gload_lds16(Agb + (size_t)r * Kb + (size_t)k0 * 2 + cb, sAb + Lb);
      gload_lds16(Bgb + (size_t)r * Kb + (size_t)k0 * 2 + cb, sBb + Lb);
    }
    __syncthreads();  // staging visible
#pragma unroll
    for (int kk = 0; kk < 2; ++kk) {
      short8 af[4], bfv[4];
#pragma unroll
      for (int t = 0; t < 4; ++t) {
        const int ch = ((kk * 4 + quad) ^ sw) * 16;
        af[t]  = *(const short8*)(sAb + (wm * 64 + t * 16 + ln) * 128 + ch);
        bfv[t] = *(const short8*)(sBb + (wn * 64 + t * 16 + ln) * 128 + ch);
      }
#pragma unroll
      for (int mt = 0; mt < 4; ++mt)
#pragma unroll
        for (int nt = 0; nt < 4; ++nt)
          acc[mt][nt] = __builtin_amdgcn_mfma_f32_16x16x32_bf16(af[mt], bfv[nt], acc[mt][nt], 0, 0, 0);
    }
  }

  // epilogue. C/D layout: col = ln, row = quad*4 + reg (measured m89/m91)
  if (MODE == 0) {
    unsigned short* out = (unsigned short*)Cout;
#pragma unroll
    for (int mt = 0; mt < 4; ++mt) {
#pragma unroll
      for (int nt = 0; nt < 4; ++nt) {
        const int gn = bn * 128 + wn * 64 + nt * 16 + ln;
        const float bv = bias[gn];
        const int pidx = gn >> 10, rem = gn & 1023;
        const int hh = rem >> 6, dd = rem & 63;
        const int gm0 = bm * 128 + wm * 64 + mt * 16 + quad * 4;
        const int bb = gm0 >> 10, ss0 = gm0 & 1023;
        if (pidx < 2) {
          // q,k: [p][b][h][s][d]
#pragma unroll
          for (int r = 0; r < 4; ++r) {
            const size_t off = ((((size_t)pidx * 16 + bb) * 16 + hh) * 1024 + (ss0 + r)) * 64 + dd;
            out[off] = f2bf(acc[mt][nt][r] + bv);
          }
        } else {
          // v: transposed [b][h][d][s]; r -> consecutive s -> one 8B store
          us4 pk;
#pragma unroll
          for (int r = 0; r < 4; ++r) pk[r] = f2bf(acc[mt][nt][r] + bv);
          const size_t off = (size_t)2 * 16777216 +
                             (((size_t)(bb * 16 + hh) * 64 + dd) * 1024 + ss0);
          *(us4*)(out + off) = pk;
        }
      }
    }
  } else {
    float* out = (float*)Cout;
#pragma unroll
    for (int mt = 0; mt < 4; ++mt) {
#pragma unroll
      for (int nt = 0; nt < 4; ++nt) {
        const int gn = bn * 128 + wn * 64 + nt * 16 + ln;
        const float bv = bias[gn];
#pragma unroll
        for (int r = 0; r < 4; ++r) {
          const int gm = bm * 128 + wm * 64 + mt * 16 + quad * 4 + r;
          out[(size_t)gm * N + gn] = acc[mt][nt][r] + bv;
        }
      }
    }
  }
}

// ---------- flash attention, S^T formulation, 2 q-subtiles per wave ----------
// Block = 256 threads = 4 waves; wave w handles 32 q rows (2 subtiles of 16).
// Block covers 128 q; 8 q-blocks per bh. 1D grid 2048, XCD-aware decode:
// bid = (sub_bh<<6)|(qt<<3)|xcd, bh = xcd*32+sub_bh -> all 8 qt blocks of one
// bh on one XCD, dispatched adjacently (K/V L2-resident).
// K,V fragments (A/B operands) are wave-uniform -> read once, reused for both
// q-subtiles. q pre-scaled by log2(e)/8 -> base-2 softmax.
// NOTE: sP writes and reads MUST stay program-ordered; writes use ushort-based
// vectors (same TBAA class as short8 reads) + explicit compiler memory barrier.
// (R5 used uint-typed writes -> compiler hoisted PV reads above them.)
__global__ __launch_bounds__(256) void attn(const unsigned short* __restrict__ Qb,
                                            const unsigned short* __restrict__ Kb_,
                                            const unsigned short* __restrict__ VTb,
                                            unsigned short* __restrict__ ctx) {
  __shared__ unsigned short sK[64 * 64];   // [kv][d], 128B rows, swizzled chunks
  __shared__ unsigned short sVT[64 * 64];  // [d][kv], 128B rows, swizzled chunks
  __shared__ unsigned short sP[128 * 72];  // [q][kv], 144B rows (pad 8 shorts)
  const int tid = threadIdx.x;
  const int w = tid >> 6, lane = tid & 63, quad = lane >> 4, ln = lane & 15;
  const int bid = blockIdx.x;
  const int xcd = bid & 7, qt = (bid >> 3) & 7, sbh = bid >> 6;
  const int bh = xcd * 32 + sbh;
  const int b = bh >> 4, h = bh & 15;

  char* sKb = (char*)sK;
  char* sVb = (char*)sVT;
  char* sPb = (char*)sP;
  const int sw = ln & 7;

  // Q fragments (B-operand), loop-invariant: 2 subtiles x 2 k-halves
  short8 bq[2][2];
#pragma unroll
  for (int s = 0; s < 2; ++s) {
    const unsigned short* Qg =
        Qb + ((size_t)bh * 1024 + (size_t)qt * 128 + w * 32 + s * 16 + ln) * 64;
    bq[s][0] = *(const short8*)(Qg + quad * 8);
    bq[s][1] = *(const short8*)(Qg + 32 + quad * 8);
  }

  f32x4 accO[2][4];
#pragma unroll
  for (int s = 0; s < 2; ++s)
#pragma unroll
    for (int nt = 0; nt < 4; ++nt) accO[s][nt] = (f32x4){0.f, 0.f, 0.f, 0.f};
  float mrun[2] = {-3e38f, -3e38f}, lrun[2] = {0.f, 0.f};

  for (int kt = 0; kt < 16; ++kt) {
    __syncthreads();  // previous tile's compute done, LDS safe to overwrite
    const char* Kg = (const char*)(Kb_ + ((size_t)bh * 1024 + (size_t)kt * 64) * 64);
    const char* Vg = (const char*)(VTb + (size_t)bh * 65536 + (size_t)kt * 64);
#pragma unroll
    for (int i = 0; i < 2; ++i) {
      const int Lb = w * 2048 + i * 1024 + lane * 16;
      const int r = Lb >> 7;
      const int c = (Lb >> 4) & 7;
      const int cb = ((c ^ (r & 7)) * 16);
      gload_lds16(Kg + (size_t)r * 128 + cb, sKb + Lb);    // K rows contiguous
      gload_lds16(Vg + (size_t)r * 2048 + cb, sVb + Lb);   // V^T rows stride 2048B
    }
    __syncthreads();  // staging visible

    // S^T = K Q^T : A = K (wave-uniform frags, reused for both subtiles)
    f32x4 accS[2][4];
#pragma unroll
    for (int s = 0; s < 2; ++s)
#pragma unroll
      for (int mt = 0; mt < 4; ++mt) accS[s][mt] = (f32x4){0.f, 0.f, 0.f, 0.f};
#pragma unroll
    for (int kk = 0; kk < 2; ++kk) {
      short8 ak[4];
#pragma unroll
      for (int mt = 0; mt < 4; ++mt)
        ak[mt] = *(const short8*)(sKb + (mt * 16 + ln) * 128 + ((kk * 4 + quad) ^ sw) * 16);
#pragma unroll
      for (int s = 0; s < 2; ++s)
#pragma unroll
        for (int mt = 0; mt < 4; ++mt)
          accS[s][mt] = __builtin_amdgcn_mfma_f32_16x16x32_bf16(ak[mt], bq[s][kk], accS[s][mt], 0, 0, 0);
    }

    // online softmax per subtile (base-2; q-logits pre-scaled by log2e).
    // Lane holds S[q = base + ln][kv = mt*16 + quad*4 + r].
#pragma unroll
    for (int s = 0; s < 2; ++s) {
      float tmax = -3e38f;
#pragma unroll
      for (int mt = 0; mt < 4; ++mt)
#pragma unroll
        for (int r = 0; r < 4; ++r) tmax = fmaxf(tmax, accS[s][mt][r]);
      tmax = fmaxf(tmax, __shfl_xor(tmax, 16));
      tmax = fmaxf(tmax, __shfl_xor(tmax, 32));
      const float mnew = fmaxf(mrun[s], tmax);
      const float alpha = exp2_fast(mrun[s] - mnew);
      mrun[s] = mnew;
      float psum = 0.f;
#pragma unroll
      for (int mt = 0; mt < 4; ++mt) {
        float p0 = exp2_fast(accS[s][mt][0] - mnew);
        float p1 = exp2_fast(accS[s][mt][1] - mnew);
        float p2 = exp2_fast(accS[s][mt][2] - mnew);
        float p3 = exp2_fast(accS[s][mt][3] - mnew);
        psum += (p0 + p1) + (p2 + p3);
        union { unsigned int u[2]; us4 v; } pu;
        pu.u[0] = cvt_pk_bf16(p0, p1);
        pu.u[1] = cvt_pk_bf16(p2, p3);
        *(us4*)(sP + (w * 32 + s * 16 + ln) * 72 + mt * 16 + quad * 4) = pu.v;  // 8B
      }
      psum += __shfl_xor(psum, 16);
      psum += __shfl_xor(psum, 32);
      lrun[s] = lrun[s] * alpha + psum;
#pragma unroll
      for (int r = 0; r < 4; ++r) {
        const float ar = __shfl(alpha, quad * 4 + r);
#pragma unroll
        for (int nt = 0; nt < 4; ++nt) accO[s][nt][r] *= ar;
      }
    }

    // Forbid hoisting the PV sP-reads above the softmax sP-writes.
    asm volatile("" ::: "memory");

    // O += P V : B = V^T (wave-uniform frags, reused for both subtiles)
#pragma unroll
    for (int kk = 0; kk < 2; ++kk) {
      short8 ap[2];
#pragma unroll
      for (int s = 0; s < 2; ++s)
        ap[s] = *(const short8*)(sPb + (w * 32 + s * 16 + ln) * 144 + kk * 64 + quad * 16);
#pragma unroll
      for (int nt = 0; nt < 4; ++nt) {
        const short8 bv = *(const short8*)(sVb + (nt * 16 + ln) * 128 + ((kk * 4 + quad) ^ sw) * 16);
#pragma unroll
        for (int s = 0; s < 2; ++s)
          accO[s][nt] = __builtin_amdgcn_mfma_f32_16x16x32_bf16(ap[s], bv, accO[s][nt], 0, 0, 0);
      }
    }
  }

  // epilogue: ctx[b][s][h*64+d] bf16
#pragma unroll
  for (int s = 0; s < 2; ++s) {
    const float inv = 1.0f / lrun[s];
#pragma unroll
    for (int r = 0; r < 4; ++r) {
      const float ivr = __shfl(inv, quad * 4 + r);
      const int sg = qt * 128 + w * 32 + s * 16 + quad * 4 + r;
#pragma unroll
      for (int nt = 0; nt < 4; ++nt) {
        const int d = nt * 16 + ln;
        ctx[((size_t)(b * 1024 + sg)) * 1024 + h * 64 + d] = f2bf(accO[s][nt][r] * ivr);
      }
    }
  }
}

// ---------- launch ----------
extern "C" void kernel_launch(void* const* d_in, const int* in_sizes, int n_in,
                              void* d_out, int out_size, void* d_ws, size_t ws_size,
                              hipStream_t stream) {
  const float* hs  = (const float*)d_in[0];
  const float* Wq  = (const float*)d_in[1];
  const float* bq  = (const float*)d_in[2];
  const float* LMq = (const float*)d_in[3];
  const float* RMq = (const float*)d_in[4];
  const float* Fq  = (const float*)d_in[5];
  const float* Wk  = (const float*)d_in[6];
  const float* bk  = (const float*)d_in[7];
  const float* LMk = (const float*)d_in[8];
  const float* RMk = (const float*)d_in[9];
  const float* Fk  = (const float*)d_in[10];
  const float* Wv  = (const float*)d_in[11];
  const float* bv  = (const float*)d_in[12];
  const float* LMv = (const float*)d_in[13];
  const float* RMv = (const float*)d_in[14];
  const float* Fv  = (const float*)d_in[15];
  const float* Wo  = (const float*)d_in[16];
  const float* bo  = (const float*)d_in[17];
  const float* LMo = (const float*)d_in[18];
  const float* RMo = (const float*)d_in[19];
  const float* Fo  = (const float*)d_in[20];
  // d_in[21] = task (always 0 branch in reference)

  // workspace layout (all 16B aligned)
  char* p = (char*)d_ws;
  unsigned short* xbf  = (unsigned short*)p; p += (size_t)16384 * 1024 * 2;   // 33.5 MB
  unsigned short* Wqkv = (unsigned short*)p; p += (size_t)3072 * 1024 * 2;    // 6.3 MB
  unsigned short* Wob  = (unsigned short*)p; p += (size_t)1024 * 1024 * 2;    // 2 MB
  float* bqkv = (float*)p; p += 3072 * 4;
  float* bob  = (float*)p; p += 1024 * 4;
  unsigned short* qkv = (unsigned short*)p; p += (size_t)3 * 16777216 * 2;    // 100.6 MB
  unsigned short* ctx = (unsigned short*)p; p += (size_t)16777216 * 2;        // 33.5 MB

  // 1/sqrt(64) * log2(e) folded into q weights+bias -> softmax in base 2
  const float qscale = 0.125f * 1.4426950408889634f;

  cast_x<<<16384, 256, 0, stream>>>(hs, xbf, 16777216 / 4);
  prep_weights<<<1024, 256, 0, stream>>>(Wq, bq, LMq, RMq, Fq, qscale, Wqkv, bqkv);
  prep_weights<<<1024, 256, 0, stream>>>(Wk, bk, LMk, RMk, Fk, 1.0f, Wqkv + 1024 * 1024, bqkv + 1024);
  prep_weights<<<1024, 256, 0, stream>>>(Wv, bv, LMv, RMv, Fv, 1.0f, Wqkv + 2 * 1024 * 1024, bqkv + 2048);
  prep_weights<<<1024, 256, 0, stream>>>(Wo, bo, LMo, RMo, Fo, 1.0f, Wob, bob);

  gemm_bt<0><<<dim3(128, 24), 256, 0, stream>>>(xbf, Wqkv, bqkv, (void*)qkv, 16384, 3072, 1024);

  attn<<<2048, 256, 0, stream>>>(qkv, qkv + 16777216, qkv + 2 * 16777216, ctx);

  gemm_bt<1><<<dim3(128, 8), 256, 0, stream>>>(ctx, Wob, bob, d_out, 16384, 1024, 1024);
}